// Round 10
// baseline (280.564 us; speedup 1.0000x reference)
//
#include <hip/hip_runtime.h>
#include <stdint.h>

typedef __attribute__((ext_vector_type(8))) unsigned short ushort8;
typedef __attribute__((ext_vector_type(8))) __bf16 bf16x8;
typedef __attribute__((ext_vector_type(4))) float f32x4;
typedef __attribute__((ext_vector_type(4))) uint32_t u32x4;

__device__ __forceinline__ unsigned short f2bf(float f) {
  union { float f; uint32_t u; } x; x.f = f;
  uint32_t u = x.u;
  uint32_t r = (u + 0x7fffu + ((u >> 16) & 1u)) >> 16;
  return (unsigned short)r;
}

__device__ __forceinline__ uint32_t pack_bf2(float lo, float hi) {
  return (uint32_t)f2bf(lo) | ((uint32_t)f2bf(hi) << 16);
}

// round-half-up bf16 pair pack: 2 adds + 1 v_perm (≡ RNE for positive non-ties)
__device__ __forceinline__ uint32_t rhu2(float lo, float hi) {
  union { float f; uint32_t u; } a, b; a.f = lo; b.f = hi;
  return __builtin_amdgcn_perm(b.u + 0x8000u, a.u + 0x8000u, 0x07060302u);
}

__device__ __forceinline__ void store_c(unsigned short* p, float v) { *p = f2bf(v); }
__device__ __forceinline__ void store_c(float* p, float v) { *p = v; }

__device__ __forceinline__ void gll16(const unsigned short* g, unsigned short* l) {
  __builtin_amdgcn_global_load_lds((const __attribute__((address_space(1))) void*)g,
                                   (__attribute__((address_space(3))) void*)l,
                                   16, 0, 0);
}

// ---------------------------------------------------------------------------
// prep: fused preprocessing, one launch.
//   blocks [0, 8192):      hsb = bf16(hs)  (fp32 -> bf16, 4 elem/thread)
//   blocks [8192, 11264):  wqT/wkT/wvT = bf16(W^T)  (32x32 tiles, z = which>>10)
// ---------------------------------------------------------------------------
__global__ __launch_bounds__(256) void prep(
    const float* __restrict__ hs, unsigned short* __restrict__ hsb,
    const float* __restrict__ wq, const float* __restrict__ wk,
    const float* __restrict__ wv,
    unsigned short* __restrict__ wqT, unsigned short* __restrict__ wkT,
    unsigned short* __restrict__ wvT) {
  __shared__ unsigned short tile[32][33];
  const int b = blockIdx.x, tid = threadIdx.x;
  if (b < 8192) {
    int i = b * 256 + tid;  // < 2097152 by construction
    float4 v = *(const float4*)(hs + (size_t)i * 4);
    uint2 p; p.x = pack_bf2(v.x, v.y); p.y = pack_bf2(v.z, v.w);
    *(uint2*)(hsb + (size_t)i * 4) = p;
  } else {
    const int which = b - 8192;
    const int z = which >> 10;
    const int w = which & 1023;
    const int c0 = (w & 31) * 32, r0 = (w >> 5) * 32;
    const float* W = (z == 0) ? wq : (z == 1) ? wk : wv;
    unsigned short* WT = (z == 0) ? wqT : (z == 1) ? wkT : wvT;
    const int x = tid & 31, y = tid >> 5;
#pragma unroll
    for (int i = 0; i < 32; i += 8)
      tile[y + i][x] = f2bf(W[(size_t)(r0 + y + i) * 1024 + c0 + x]);
    __syncthreads();
#pragma unroll
    for (int i = 0; i < 32; i += 8)
      WT[(size_t)(c0 + y + i) * 1024 + r0 + x] = tile[x][y + i];
  }
}

__global__ void transpose_w(const float* __restrict__ W,
                            unsigned short* __restrict__ WT) {
  __shared__ unsigned short tile[32][33];
  int c0 = blockIdx.x * 32, r0 = blockIdx.y * 32;
  int x = threadIdx.x, y = threadIdx.y;
#pragma unroll
  for (int i = 0; i < 32; i += 8)
    tile[y + i][x] = f2bf(W[(size_t)(r0 + y + i) * 1024 + c0 + x]);
  __syncthreads();
#pragma unroll
  for (int i = 0; i < 32; i += 8)
    WT[(size_t)(c0 + y + i) * 1024 + r0 + x] = tile[x][y + i];
}

// ---------------------------------------------------------------------------
// GEMM R19 (gemm7): R14's 3-stage counted-vmcnt pipeline, remap DELETED
// (natural dispatch order — the remap, not the pipeline, is the suspected
// R14 regression; this isolates it).
// 128x128 tile, BK=32, 256 thr (4 waves as 2m x 2n, each 64x64 out).
// 3-slot LDS 48 KB -> 3 blocks/CU (12 waves/CU):
//   prologue: STAGE(0->slot0), STAGE(1->slot1)
//   iter t:   s_waitcnt vmcnt(4)   // retire STAGE(t); STAGE(t+1) in flight
//             s_barrier            // slot t%3 ready for all waves
//             STAGE(t+2 -> slot (t+2)%3)
//              8 ds_read_b128, 16 MFMA
// Never vmcnt(0) in the loop (T4). Slot overwritten was last read at t-1,
// reads consumed (lgkm-waited) before that wave's barrier(t).
// Both-sides XOR swizzle (BK=32: chunk' = chunk ^ (row&3)); source col
// pre-swizzled (lane-constant (lane>>2)&3), reads XOR fq ^ (fr&3).
// sc0: epilogue scale when z==0 (folds attn head_scale*log2e into q proj).
// ---------------------------------------------------------------------------
template <typename OutT>
__global__ __launch_bounds__(256, 3) void gemm7(
    const unsigned short* A,
    const unsigned short* BT0, const unsigned short* BT1, const unsigned short* BT2,
    OutT* C0, OutT* C1, OutT* C2,
    int M, int N, int K, float sc0) {
  const int z = blockIdx.z;
  const unsigned short* BT = (z == 0) ? BT0 : (z == 1) ? BT1 : BT2;
  OutT* C = (z == 0) ? C0 : (z == 1) ? C1 : C2;
  const float sc = (z == 0) ? sc0 : 1.0f;

  __shared__ __attribute__((aligned(16))) unsigned short As[3][128 * 32];
  __shared__ __attribute__((aligned(16))) unsigned short Bs[3][128 * 32];

  const int tid = threadIdx.x;
  const int wave = tid >> 6, lane = tid & 63;
  const int fr = lane & 15, fq = lane >> 4;
  const int wm = wave >> 1, wn = wave & 1;
  const int bm = blockIdx.y * 128, bn = blockIdx.x * 128;

  // staging: per wave per stage, 2 gll16 A + 2 gll16 B (1 KB = 16 rows x 64B).
  // lane covers (row = i*64 + wave*16 + (lane>>2), chunk = lane&3); source
  // chunk pre-swizzled by row&3 = (lane>>2)&3 (instruction-invariant).
  const int r4 = lane >> 2, c4 = lane & 3;
  const int scs = (c4 ^ (r4 & 3)) * 8;
  const unsigned short* Ag = A + (size_t)(bm + wave * 16 + r4) * K + scs;
  const unsigned short* Bg = BT + (size_t)(bn + wave * 16 + r4) * K + scs;

  f32x4 acc[4][4] = {};
  const int NT = K >> 5;

  auto STAGE = [&](int buf, int t) {
    const size_t k0 = (size_t)t * 32;
    gll16(Ag + k0, &As[buf][(wave * 16) * 32]);
    gll16(Ag + k0 + (size_t)64 * K, &As[buf][(64 + wave * 16) * 32]);
    gll16(Bg + k0, &Bs[buf][(wave * 16) * 32]);
    gll16(Bg + k0 + (size_t)64 * K, &Bs[buf][(64 + wave * 16) * 32]);
  };

  // read-side swizzle: row = wm*64 + mt*16 + fr -> row&3 = fr&3 (const)
  const int rxr = (fq ^ (fr & 3)) * 8;

  STAGE(0, 0);
  STAGE(1, 1);

  int bc = 0, bs = 2;
  for (int t = 0; t < NT; ++t) {
    if (t + 1 < NT)
      asm volatile("s_waitcnt vmcnt(4)" ::: "memory");
    else
      asm volatile("s_waitcnt vmcnt(0)" ::: "memory");
    __builtin_amdgcn_s_barrier();

    if (t + 2 < NT) STAGE(bs, t + 2);

    bf16x8 af[4], bfr[4];
#pragma unroll
    for (int mt = 0; mt < 4; mt++)
      af[mt] = *(const bf16x8*)&As[bc][(wm * 64 + mt * 16 + fr) * 32 + rxr];
#pragma unroll
    for (int nt = 0; nt < 4; nt++)
      bfr[nt] = *(const bf16x8*)&Bs[bc][(wn * 64 + nt * 16 + fr) * 32 + rxr];
#pragma unroll
    for (int mt = 0; mt < 4; mt++)
#pragma unroll
      for (int nt = 0; nt < 4; nt++)
        acc[mt][nt] = __builtin_amdgcn_mfma_f32_16x16x32_bf16(af[mt], bfr[nt], acc[mt][nt], 0, 0, 0);

    bc = (bc == 2) ? 0 : bc + 1;
    bs = (bs == 2) ? 0 : bs + 1;
  }

#pragma unroll
  for (int mt = 0; mt < 4; mt++)
#pragma unroll
    for (int nt = 0; nt < 4; nt++)
#pragma unroll
      for (int r = 0; r < 4; r++) {
        int row = bm + wm * 64 + mt * 16 + fq * 4 + r;
        int col = bn + wn * 64 + nt * 16 + fr;
        store_c(&C[(size_t)row * N + col], acc[mt][nt][r] * sc);
      }
}

// ---------------------------------------------------------------------------
// Flash attention (R17/R18 verified, 77 µs): T14 async V + free-drain
// barriers + scalar-cast softmax (HW cvt_pk), q pre-scaled, setprio.
// ---------------------------------------------------------------------------
__global__ __launch_bounds__(256, 4) void attn_kernel(
    const unsigned short* q, const unsigned short* k,
    const unsigned short* v, unsigned short* o) {
  const int S = 2048, E = 1024;
  __shared__ __attribute__((aligned(16))) unsigned short Ksb[2 * 64 * 64];
  __shared__ __attribute__((aligned(16))) unsigned short Vtb[64 * 64];

  const int tid = threadIdx.x;
  const int wave = tid >> 6, lane = tid & 63;
  const int fr = lane & 15, fq = lane >> 4;
  const int q0 = blockIdx.x * 128;
  const int bh = blockIdx.y;
  const int b = bh >> 4, h = bh & 15;
  const size_t base = ((size_t)b * S) * E + (size_t)h * 64;

  bf16x8 aq[2][2];
#pragma unroll
  for (int qg = 0; qg < 2; qg++)
#pragma unroll
    for (int ks = 0; ks < 2; ks++)
      aq[qg][ks] = *(const bf16x8*)&q[base +
          (size_t)(q0 + qg * 64 + wave * 16 + fr) * E + ks * 32 + fq * 8];

  ushort8 ones_u;
#pragma unroll
  for (int j = 0; j < 8; j++) ones_u[j] = 0x3F80;  // bf16 1.0
  bf16x8 onesf = *(bf16x8*)&ones_u;

  f32x4 ot[2][4] = {};
  f32x4 osum[2] = {};

  const int srow = lane >> 3;
  const int scol = (((lane & 7) ^ srow) << 3);
  const unsigned short* Kg = k + base + (size_t)(wave * 16 + srow) * E + scol;

  const int rp = (tid & 31) * 2;
  const int dcv = (tid >> 5) * 8;
  const int u_ = rp & 31;
  const int slot = 32 * (rp >> 5) + 8 * ((u_ & 15) >> 2) + 4 * (u_ >> 4) + (u_ & 3);
  const unsigned short* Vg = v + base + (size_t)rp * E + dcv;

  const int rx = (fr & 7) << 3;

  // prologue: K chunk 0 -> LDS (in flight), V chunk 0 -> regs (in flight)
  gll16(Kg, &Ksb[wave * 1024]);
  gll16(Kg + 8 * (size_t)E, &Ksb[wave * 1024 + 512]);
  u32x4 va = *(const u32x4*)(Vg);
  u32x4 vb = *(const u32x4*)(Vg + E);

  int cur = 0;
  for (int t = 0; t < 32; t++) {
    const int nxt = cur ^ 4096;

    __syncthreads();  // A: drains K[t] + va/vb — all issued a full phase ago

    // stage Vt from regs; overlaps with S^T below (different consumers)
#pragma unroll
    for (int w = 0; w < 4; w++) {
      uint32_t lo = __builtin_amdgcn_perm(vb[w], va[w], 0x05040100u);
      uint32_t hi = __builtin_amdgcn_perm(vb[w], va[w], 0x07060302u);
      int d = dcv + 2 * w;
      *(uint32_t*)&Vtb[d * 64 + (slot ^ ((2 * w) << 3))] = lo;
      *(uint32_t*)&Vtb[(d + 1) * 64 + (slot ^ ((2 * w + 1) << 3))] = hi;
    }

    // S^T: reads Ksb[cur] only (visible since barrier A)
    f32x4 st[2][4] = {};
    __builtin_amdgcn_s_setprio(1);
#pragma unroll
    for (int ks = 0; ks < 2; ks++) {
#pragma unroll
      for (int tt = 0; tt < 4; tt++) {
        bf16x8 ak = *(const bf16x8*)&Ksb[cur + (tt * 16 + fr) * 64 +
                                         ((ks * 32 + fq * 8) ^ rx)];
        st[0][tt] = __builtin_amdgcn_mfma_f32_16x16x32_bf16(ak, aq[0][ks], st[0][tt], 0, 0, 0);
        st[1][tt] = __builtin_amdgcn_mfma_f32_16x16x32_bf16(ak, aq[1][ks], st[1][tt], 0, 0, 0);
      }
    }
    __builtin_amdgcn_s_setprio(0);

    __syncthreads();  // B: Vt visible; no vmem outstanding -> free drain

    // prefetch chunk t+1: K -> LDS[nxt] (zero reg cost), V -> regs (8 VGPR,
    // live across exp2+PV; drained for free at next barrier A)
    if (t < 31) {
      const size_t poff = (size_t)(t + 1) * 64 * E;
      gll16(Kg + poff, &Ksb[nxt + wave * 1024]);
      gll16(Kg + poff + 8 * (size_t)E, &Ksb[nxt + wave * 1024 + 512]);
      va = *(const u32x4*)(Vg + poff);
      vb = *(const u32x4*)(Vg + poff + E);
    }

    // exp2 (scale pre-folded into q) + bf16 via scalar casts (HW cvt_pk)
    bf16x8 bp[2][2];  // [c][qg]
#pragma unroll
    for (int c = 0; c < 2; c++)
#pragma unroll
      for (int qg = 0; qg < 2; qg++) {
        bf16x8 vv;
#pragma unroll
        for (int j = 0; j < 8; j++)
          vv[j] = (__bf16)__builtin_amdgcn_exp2f(st[qg][2 * c + (j >> 2)][j & 3]);
        bp[c][qg] = vv;
      }

    // PV: reads Vtb (visible since barrier B)
    __builtin_amdgcn_s_setprio(1);
#pragma unroll
    for (int c = 0; c < 2; c++) {
#pragma unroll
      for (int dt = 0; dt < 4; dt++) {
        bf16x8 av = *(const bf16x8*)&Vtb[(dt * 16 + fr) * 64 +
                                         ((c * 32 + fq * 8) ^ rx)];
        ot[0][dt] = __builtin_amdgcn_mfma_f32_16x16x32_bf16(av, bp[c][0], ot[0][dt], 0, 0, 0);
        ot[1][dt] = __builtin_amdgcn_mfma_f32_16x16x32_bf16(av, bp[c][1], ot[1][dt], 0, 0, 0);
      }
      osum[0] = __builtin_amdgcn_mfma_f32_16x16x32_bf16(onesf, bp[c][0], osum[0], 0, 0, 0);
      osum[1] = __builtin_amdgcn_mfma_f32_16x16x32_bf16(onesf, bp[c][1], osum[1], 0, 0, 0);
    }
    __builtin_amdgcn_s_setprio(0);

    cur = nxt;
  }

#pragma unroll
  for (int qg = 0; qg < 2; qg++) {
    float inv = 1.0f / osum[qg][0];
    size_t rowbase = base + (size_t)(q0 + qg * 64 + wave * 16 + fr) * E;
#pragma unroll
    for (int dt = 0; dt < 4; dt++) {
      uint32_t w0 = rhu2(ot[qg][dt][0] * inv, ot[qg][dt][1] * inv);
      uint32_t w1 = rhu2(ot[qg][dt][2] * inv, ot[qg][dt][3] * inv);
      *(uint32_t*)&o[rowbase + dt * 16 + fq * 4] = w0;
      *(uint32_t*)&o[rowbase + dt * 16 + fq * 4 + 2] = w1;
    }
  }
}

// ---------------------------------------------------------------------------
// ws: 3 x 1M (weights) + 3 x 8M (q/k/v) shorts = 54 MB.
// bf16 hidden_states lives in d_out's first 16 MB (dead before final GEMM).
// woT reuses wqT's slot (transposed only after the QKV GEMM has consumed
// wqT). Final GEMM writes fp32 to d_out.
// ---------------------------------------------------------------------------
extern "C" void kernel_launch(void* const* d_in, const int* in_sizes, int n_in,
                              void* d_out, int out_size, void* d_ws, size_t ws_size,
                              hipStream_t stream) {
  const float* hs = (const float*)d_in[0];
  const float* wq = (const float*)d_in[1];
  const float* wk = (const float*)d_in[2];
  const float* wv = (const float*)d_in[3];
  const float* wo = (const float*)d_in[4];
  unsigned short* ws = (unsigned short*)d_ws;

  unsigned short* wqT = ws;
  unsigned short* wkT = ws + 1048576;
  unsigned short* wvT = ws + 2097152;
  unsigned short* woT = wqT;
  unsigned short* qb  = ws + 3145728;
  unsigned short* kb  = qb + 8388608;
  unsigned short* vb  = kb + 8388608;
  unsigned short* ob  = qb;
  unsigned short* hsb = (unsigned short*)d_out;
  float* out = (float*)d_out;

  const int M = 8192, N = 1024, K = 1024;
  const float KSC = 0.125f * 1.44269504088896341f;  // head_scale * log2(e)

  // fused: hs cvt (blocks 0..8191) + wq/wk/wv transposes (blocks 8192..11263)
  prep<<<dim3(11264), 256, 0, stream>>>(hs, hsb, wq, wk, wv, wqT, wkT, wvT);

  // natural order: x = bn (8), y = bm (64), z = 3 -> 1536 blocks, 3/CU
  gemm7<unsigned short><<<dim3(8, 64, 3), 256, 0, stream>>>(
      hsb, wqT, wkT, wvT, qb, kb, vb, M, N, K, KSC);

  dim3 tb(32, 8);
  transpose_w<<<dim3(32, 32), tb, 0, stream>>>(wo, woT);

  attn_kernel<<<dim3(2048 / 128, 64), 256, 0, stream>>>(qb, kb, vb, ob);

  gemm7<float><<<dim3(8, 64, 1), 256, 0, stream>>>(
      ob, woT, woT, woT, out, out, out, M, N, K, 1.0f);
}